// Round 9
// baseline (708.004 us; speedup 1.0000x reference)
//
#include <hip/hip_runtime.h>
#include <math.h>

#define B_ 8192
#define L_ 49
#define C_ 512
#define R_ 128

typedef short   bf16x8 __attribute__((ext_vector_type(8)));
typedef unsigned short u16x8 __attribute__((ext_vector_type(8)));
typedef float   f32x4  __attribute__((ext_vector_type(4)));

// ws layout (ushort elements) — ALL weights wave-fragment-contiguous
// lwf : [nt=8][ks=16][lane=64][8]   = lw[nt*16+(lane&15)][ks*32+(lane>>4)*8+j]
// gwf : same packing of g_reduce_w
// wb3f: [tap=9][f=4][ks=2][lane=64][8]  = w3[f*16+(lane&15)][ks*32+(lane>>4)*8+j][tap]
// wb5f: [tap=25][f=4][ks=2][lane=64][8] = w5[...][tap]
// cwf : [nf=32][ks=4][lane=64][8]   = cw[nf*16+(lane&15)][ks*32+(lane>>4)*8+j]
#define WS_LWF   0           // 65536
#define WS_WB3F  65536       // 36864
#define WS_WB5F  102400      // 102400
#define WS_GWF   204800      // 65536
#define WS_CWF   270336      // 65536

// LDS layout (bytes), total 76960 -> 2 blocks/CU
#define SM_XB    0           // ush[49][256] swizzled = 25088
#define SM_XLP   25088       // ush[121][136] padded x_l image = 32912
#define SM_MAXB  58000       // bf16[8][256] = 4096
#define SM_SUMF  62096       // f32[8][256] = 8192
#define SM_GA    70288       // bf16[2][256] = 1024
#define SM_G     71312       // f32[2][128] = 1024
#define SM_HB    72336       // bf16[128] = 256
#define SM_CA    72592       // f32[512] = 2048
#define SM_SPW   74640       // f32[8][64] = 2048
#define SM_SP    76688       // f32[64] = 256
#define SM_GDOT  76944       // f32[4] = 16
#define SM_TOT   76960

#define XLP_N    16456       // 121*136 ushorts
#define DBIAS    3264        // (2*11+2)*136 : bias so all ds offsets are non-negative

__device__ __forceinline__ float bf2f(unsigned short u) {
    union { float f; unsigned int i; } v; v.i = ((unsigned int)u) << 16; return v.f;
}
__device__ __forceinline__ unsigned short f2bf(float f) {
    union { float f; unsigned int i; } v; v.f = f;
    unsigned int r = v.i + 0x7fffu + ((v.i >> 16) & 1u);
    return (unsigned short)(r >> 16);
}
// packed f32x2 -> bf16x2 (RTNE, same as f2bf)
__device__ __forceinline__ unsigned int pkbf(float a, float b) {
    unsigned int r;
    asm("v_cvt_pk_bf16_f32 %0, %1, %2" : "=v"(r) : "v"(a), "v"(b));
    return r;
}
__device__ __forceinline__ float star_relu(float x, float sc, float bi) {
    float r = fmaxf(x, 0.f);
    return sc * r * r + bi;
}
__device__ __forceinline__ float sigmoidf_(float x) {
    return 1.f / (1.f + __expf(-x));
}
__device__ __forceinline__ int prowf(int lp) {       // padded row index
    int pi = lp / 7, pj = lp - pi * 7;
    return (pi + 2) * 11 + (pj + 2);
}

// ---------------- pre-pass: convert + repack weights to fragment-contiguous bf16 ----------------
__global__ void cvt_weights(const float* __restrict__ lw, const float* __restrict__ w3,
                            const float* __restrict__ w5, const float* __restrict__ gw,
                            const float* __restrict__ cw, unsigned short* __restrict__ ws)
{
    int t = blockIdx.x * blockDim.x + threadIdx.x;
    int stride = gridDim.x * blockDim.x;
    // lwf / gwf
    for (int i = t; i < 65536; i += stride) {
        int j = i & 7, lane = (i >> 3) & 63, ks = (i >> 9) & 15, nt = i >> 13;
        int n = nt * 16 + (lane & 15);
        int k = ks * 32 + (lane >> 4) * 8 + j;
        ws[WS_LWF + i] = f2bf(lw[n * 512 + k]);
        ws[WS_GWF + i] = f2bf(gw[n * 512 + k]);
    }
    // cwf: [nf][ks][lane][8]
    for (int i = t; i < 65536; i += stride) {
        int j = i & 7, lane = (i >> 3) & 63, ks = (i >> 9) & 3, nf = i >> 11;
        int c = nf * 16 + (lane & 15);
        int k = ks * 32 + (lane >> 4) * 8 + j;
        ws[WS_CWF + i] = f2bf(cw[c * 128 + k]);
    }
    // wb3f
    for (int i = t; i < 36864; i += stride) {
        int j = i & 7, lane = (i >> 3) & 63, ks = (i >> 9) & 1, f = (i >> 10) & 3, tap = i >> 12;
        int oc = f * 16 + (lane & 15);
        int ic = ks * 32 + (lane >> 4) * 8 + j;
        ws[WS_WB3F + i] = f2bf(w3[(oc * 64 + ic) * 9 + tap]);
    }
    // wb5f
    for (int i = t; i < 102400; i += stride) {
        int j = i & 7, lane = (i >> 3) & 63, ks = (i >> 9) & 1, f = (i >> 10) & 3, tap = i >> 12;
        int oc = f * 16 + (lane & 15);
        int ic = ks * 32 + (lane >> 4) * 8 + j;
        ws[WS_WB5F + i] = f2bf(w5[(oc * 64 + ic) * 25 + tap]);
    }
}

// ---------------- conv tap-GEMM on padded x_l image: address = base + compile-time tap offset ----------------
template <int NTAP, int KD, int PAD, int COLBASE>
__device__ __forceinline__ void conv_mfma(const unsigned short* __restrict__ s_xlp,
                                          const unsigned short* __restrict__ wtbf,
                                          int m16, int kg, int ln, int f, f32x4 C[4])
{
    int base[4];
    #pragma unroll
    for (int mf = 0; mf < 4; ++mf) {
        int lp = min(mf * 16 + m16, 48);                 // clamped; lp>=49 lanes masked in epilogue
        base[mf] = prowf(lp) * 136 + COLBASE + kg * 8 - DBIAS;
    }
    #pragma unroll
    for (int tap = 0; tap < NTAP; ++tap) {
        const int doff = ((tap / KD - PAD) * 11 + (tap % KD - PAD)) * 136 + DBIAS;  // compile-time
        #pragma unroll
        for (int ks = 0; ks < 2; ++ks) {
            bf16x8 bb = *(const bf16x8*)(wtbf + ((tap * 4 + f) * 2 + ks) * 512 + ln * 8);
            #pragma unroll
            for (int mf = 0; mf < 4; ++mf) {
                bf16x8 a = *(const bf16x8*)&s_xlp[base[mf] + doff + ks * 32];
                C[mf] = __builtin_amdgcn_mfma_f32_16x16x32_bf16(a, bb, C[mf], 0, 0, 0);
            }
        }
    }
}

// ---------------- main fused kernel: one block per batch ----------------
__global__ __launch_bounds__(512, 4)
void mafn_fused(const float* __restrict__ x,
                const float* __restrict__ b3, const float* __restrict__ b5,
                const float* __restrict__ cb, const float* __restrict__ sw,
                const float* __restrict__ sb, const float* __restrict__ ssc,
                const float* __restrict__ sbi,
                const unsigned short* __restrict__ ws,
                float* __restrict__ out)
{
    __shared__ __align__(16) unsigned char smem[SM_TOT];
    unsigned short* s_xb   = (unsigned short*)(smem + SM_XB);
    unsigned short* s_xlp  = (unsigned short*)(smem + SM_XLP);
    unsigned short* s_maxb = (unsigned short*)(smem + SM_MAXB);
    float*          s_sumf = (float*)(smem + SM_SUMF);
    unsigned short* s_ga   = (unsigned short*)(smem + SM_GA);
    float*          s_g    = (float*)(smem + SM_G);
    unsigned short* s_hb   = (unsigned short*)(smem + SM_HB);
    float*          s_ca   = (float*)(smem + SM_CA);
    float*          s_spw  = (float*)(smem + SM_SPW);
    float*          s_sp   = (float*)(smem + SM_SP);
    float*          s_gdot = (float*)(smem + SM_GDOT);

    const int b = blockIdx.x, t = threadIdx.x;
    const int wv = t >> 6, ln = t & 63;
    const int m16 = ln & 15, kg = ln >> 4;
    const float scale = ssc[0], sbias = sbi[0];

    const unsigned short* lwf  = ws + WS_LWF;
    const unsigned short* wb3f = ws + WS_WB3F;
    const unsigned short* wb5f = ws + WS_WB5F;
    const unsigned short* gwf  = ws + WS_GWF;
    const unsigned short* cwf  = ws + WS_CWF;

    f32x4 accA[4];       // x_l accumulators (n = wv*16+m16)
    f32x4 accG;          // g accumulator
    {
        const f32x4 z = {0.f, 0.f, 0.f, 0.f};
        #pragma unroll
        for (int mf = 0; mf < 4; ++mf) accA[mf] = z;
        accG = z;
    }

    // zero the padded x_l image once (borders must be 0; interior overwritten in P4)
    for (int i = t; i < XLP_N / 2; i += 512) ((unsigned int*)s_xlp)[i] = 0;

    const int l0 = wv * 6;
    const int nl = (wv < 7) ? 6 : 7;      // rows 42..48 for wave 7

    // ================= K-split halves: P1 load / P2 reduce / P3 GEMMs =================
    #pragma unroll 1
    for (int h = 0; h < 2; ++h) {
        // ---- P1: load x half (f32), partials, bf16 -> swizzled LDS ----
        {
            const float4* x4 = (const float4*)(x + (size_t)b * (L_ * C_)) + h * 64;
            float4 mx = {-3.4e38f, -3.4e38f, -3.4e38f, -3.4e38f};
            float4 sm = {0.f, 0.f, 0.f, 0.f};
            for (int li = 0; li < nl; ++li) {
                int l = l0 + li;
                float4 v = x4[l * 128 + ln];
                mx.x = fmaxf(mx.x, v.x); mx.y = fmaxf(mx.y, v.y);
                mx.z = fmaxf(mx.z, v.z); mx.w = fmaxf(mx.w, v.w);
                sm.x += v.x; sm.y += v.y; sm.z += v.z; sm.w += v.w;
                uint2 p; p.x = pkbf(v.x, v.y); p.y = pkbf(v.z, v.w);
                int chunk = (ln >> 1) ^ (l & 7);
                *(uint2*)&s_xb[l * 256 + chunk * 8 + (ln & 1) * 4] = p;
            }
            uint2 pm; pm.x = pkbf(mx.x, mx.y); pm.y = pkbf(mx.z, mx.w);
            *(uint2*)&s_maxb[wv * 256 + ln * 4] = pm;
            *(float4*)&s_sumf[wv * 256 + ln * 4] = sm;
        }
        __syncthreads();

        // ---- P2: finalize max/avg for this half -> bf16 A rows ----
        {
            if (t < 256) {
                int c = t;
                float m = bf2f(s_maxb[c]);
                #pragma unroll
                for (int i = 1; i < 8; ++i) m = fmaxf(m, bf2f(s_maxb[i * 256 + c]));
                s_ga[c] = f2bf(m);                       // exact: m already a bf16 value
            } else {
                int c = t - 256;
                float s = 0.f;
                #pragma unroll
                for (int i = 0; i < 8; ++i) s += s_sumf[i * 256 + c];
                s_ga[256 + c] = f2bf(s * (1.f / 49.f));
            }
        }
        __syncthreads();

        // ---- P3: all 8 waves: x_l MFMA, then g MFMA ----
        {
            int rowA[4];
            #pragma unroll
            for (int mf = 0; mf < 4; ++mf) rowA[mf] = min(mf * 16 + m16, 48);
            #pragma unroll 2
            for (int ks = 0; ks < 8; ++ks) {
                bf16x8 bb = *(const bf16x8*)(lwf + (wv * 16 + h * 8 + ks) * 512 + ln * 8);
                #pragma unroll
                for (int mf = 0; mf < 4; ++mf) {
                    int chunk = (ks * 4 + kg) ^ (rowA[mf] & 7);
                    bf16x8 a = *(const bf16x8*)&s_xb[rowA[mf] * 256 + chunk * 8];
                    accA[mf] = __builtin_amdgcn_mfma_f32_16x16x32_bf16(a, bb, accA[mf], 0, 0, 0);
                }
            }
            const bf16x8 zz = {0,0,0,0,0,0,0,0};
            #pragma unroll 4
            for (int ks = 0; ks < 8; ++ks) {
                bf16x8 a = (m16 < 2) ? *(const bf16x8*)&s_ga[m16 * 256 + ks * 32 + kg * 8] : zz;
                bf16x8 bb = *(const bf16x8*)(gwf + (wv * 16 + h * 8 + ks) * 512 + ln * 8);
                accG = __builtin_amdgcn_mfma_f32_16x16x32_bf16(a, bb, accG, 0, 0, 0);
            }
        }
        __syncthreads();
    }

    // ---- P4: store x_l into padded image + g/hb (kg==0 lanes) ----
    {
        const int n = wv * 16 + m16;
        #pragma unroll
        for (int mf = 0; mf < 4; ++mf) {
            #pragma unroll
            for (int rp = 0; rp < 2; ++rp) {
                unsigned int u = pkbf(accA[mf][rp * 2], accA[mf][rp * 2 + 1]);
                int lp0 = mf * 16 + kg * 4 + rp * 2;
                if (lp0 < 49)     s_xlp[prowf(lp0) * 136 + n]     = (unsigned short)u;
                if (lp0 + 1 < 49) s_xlp[prowf(lp0 + 1) * 136 + n] = (unsigned short)(u >> 16);
            }
        }
        if (kg == 0) {
            float g1v = star_relu(accG[0], scale, sbias);   // row 0 = max -> g1
            float g2v = star_relu(accG[1], scale, sbias);   // row 1 = avg -> g2
            s_g[n] = g1v;
            s_g[128 + n] = g2v;
            s_hb[n] = f2bf(g1v + g2v);
        }
    }
    __syncthreads();

    // ---- P5: waves 0-3: conv5  ||  waves 4-7: conv3 + c_aggr(MFMA) + gdot ----
    const int f_ = wv & 3;
    const int oc_ = f_ * 16 + m16;
    {
        f32x4 C[4];
        const f32x4 z = {0.f, 0.f, 0.f, 0.f};
        #pragma unroll
        for (int mf = 0; mf < 4; ++mf) C[mf] = z;

        if (wv < 4) {
            conv_mfma<25, 5, 2, 64>(s_xlp, wb5f, m16, kg, ln, f_, C);   // 200 MFMA
        } else {
            conv_mfma< 9, 3, 1,  0>(s_xlp, wb3f, m16, kg, ln, f_, C);   // 72 MFMA
            // c_aggr = sigmoid(cw·(g1+g2) + 2cb) via MFMA: A row0 = hb
            bf16x8 aH[4];
            #pragma unroll
            for (int ks = 0; ks < 4; ++ks) {
                bf16x8 tt = {0,0,0,0,0,0,0,0};
                if (m16 == 0) tt = *(const bf16x8*)&s_hb[ks * 32 + kg * 8];
                aH[ks] = tt;
            }
            const int nf0 = (wv - 4) * 8;
            #pragma unroll 2
            for (int q = 0; q < 8; ++q) {
                int nf = nf0 + q;
                f32x4 acc = z;
                #pragma unroll
                for (int ks = 0; ks < 4; ++ks) {
                    bf16x8 bb = *(const bf16x8*)(cwf + ((nf * 4 + ks) * 64 + ln) * 8);
                    acc = __builtin_amdgcn_mfma_f32_16x16x32_bf16(aH[ks], bb, acc, 0, 0, 0);
                }
                if (kg == 0) {
                    int c = nf * 16 + m16;
                    s_ca[c] = sigmoidf_(acc[0] + 2.f * cb[c]);
                }
            }
            if (wv == 7) {
                float p = s_g[ln] * sw[128 + ln] + s_g[128 + ln] * sw[256 + ln]
                        + s_g[ln + 64] * sw[128 + ln + 64] + s_g[128 + ln + 64] * sw[256 + ln + 64];
                #pragma unroll
                for (int off = 32; off > 0; off >>= 1) p += __shfl_xor(p, off);
                if (ln == 0) s_gdot[0] = p;
            }
        }

        // epilogue: star_relu + sw-dot, reduce over this wave's 16 channels
        const bool is5 = (wv < 4);
        const int ch = is5 ? 64 + oc_ : oc_;
        const float bias = is5 ? b5[oc_] : b3[oc_];
        const float sww = sw[ch];
        #pragma unroll
        for (int mf = 0; mf < 4; ++mf) {
            #pragma unroll
            for (int rg = 0; rg < 4; ++rg) {
                int lp = mf * 16 + kg * 4 + rg;
                float v = (lp < 49) ? star_relu(C[mf][rg] + bias, scale, sbias) * sww : 0.f;
                v += __shfl_xor(v, 1);
                v += __shfl_xor(v, 2);
                v += __shfl_xor(v, 4);
                v += __shfl_xor(v, 8);
                if (m16 == 0 && lp < 49) s_spw[wv * 64 + lp] = v;
            }
        }
    }
    __syncthreads();

    // ---- P6: spatial gate (sum 8 wave partials) ----
    if (t < 49) {
        float s = s_gdot[0] + sb[0];
        #pragma unroll
        for (int w = 0; w < 8; ++w) s += s_spw[w * 64 + t];
        s_sp[t] = sigmoidf_(s);
    }
    __syncthreads();

    // ---- P7: out = x * ca[c] * sp[l] (x re-read f32, L2-hot) ----
    {
        const float4* x4 = (const float4*)(x + (size_t)b * (L_ * C_));
        float4* o4 = (float4*)(out + (size_t)b * (L_ * C_));
        const float4* ca4 = (const float4*)s_ca;
        for (int i = t; i < 49 * 128; i += 512) {
            int l = i >> 7, c4 = i & 127;
            float4 xv = x4[i];
            float g = s_sp[l];
            float4 cv = ca4[c4];
            float4 ov;
            ov.x = xv.x * cv.x * g;
            ov.y = xv.y * cv.y * g;
            ov.z = xv.z * cv.z * g;
            ov.w = xv.w * cv.w * g;
            o4[i] = ov;
        }
    }
}

extern "C" void kernel_launch(void* const* d_in, const int* in_sizes, int n_in,
                              void* d_out, int out_size, void* d_ws, size_t ws_size,
                              hipStream_t stream) {
    (void)in_sizes; (void)n_in; (void)ws_size; (void)out_size;
    const float* x    = (const float*)d_in[0];
    const float* g_w  = (const float*)d_in[1];
    const float* l_w  = (const float*)d_in[2];
    const float* w3   = (const float*)d_in[3];
    const float* b3   = (const float*)d_in[4];
    const float* w5   = (const float*)d_in[5];
    const float* b5   = (const float*)d_in[6];
    const float* cw   = (const float*)d_in[7];
    const float* cb   = (const float*)d_in[8];
    const float* sw   = (const float*)d_in[9];
    const float* sb   = (const float*)d_in[10];
    const float* ssc  = (const float*)d_in[11];
    const float* sbi  = (const float*)d_in[12];
    float* outp = (float*)d_out;
    unsigned short* ws = (unsigned short*)d_ws;

    cvt_weights<<<dim3(512), dim3(256), 0, stream>>>(l_w, w3, w5, g_w, cw, ws);
    mafn_fused<<<dim3(B_), dim3(512), 0, stream>>>(
        x, b3, b5, cb, sw, sb, ssc, sbi, ws, outp);
}